// Round 22
// baseline (1180.432 us; speedup 1.0000x reference)
//
#include <hip/hip_runtime.h>

#define BATCH 2
#define NH    16
#define SEQ   2048
#define DH    64
#define NW    16            // waves per block (1024 threads)
#define KSPAN 128           // k-cols per wave
#define CHUNK 64            // k-cols per chunk
#define NCHK  (KSPAN/CHUNK) // 2 chunks per wave
#define SUBT  32            // MFMA subtile cols

typedef __attribute__((ext_vector_type(8))) short          bf16x8;
typedef __attribute__((ext_vector_type(4))) float          f32x4;
typedef __attribute__((ext_vector_type(2))) unsigned int   u32x2;
typedef __attribute__((ext_vector_type(4))) int            i32x4;
typedef __attribute__((ext_vector_type(4))) _Float16       f16x4;

__device__ __forceinline__ unsigned short f2bf(float f) {   // RNE (Q only)
    union { float f; unsigned int i; } c;
    c.f = f;
    unsigned int x = c.i;
    x += 0x7fffu + ((x >> 16) & 1u);
    return (unsigned short)(x >> 16);
}
__device__ __forceinline__ unsigned int pkt(float lo, float hi) {   // trunc bf16 pair
    union { float f; unsigned int u; } a, b;
    a.f = lo; b.f = hi;
    return (b.u & 0xFFFF0000u) | (a.u >> 16);
}
__device__ __forceinline__ float bfu2f(unsigned short u) {
    union { unsigned int i; float f; } c;
    c.i = ((unsigned int)u) << 16;
    return c.f;
}

// Single-pass SDPA, 16 waves/block (4/SIMD) x KSPAN=128 each.
// LDS: Pbig 64 KB + ArenaH 32 KB (f16 pivots; Lsum overlays; accO deposits -> Pbig).
template<bool ISBYTE>
__global__ __launch_bounds__(1024)
void sdpa_fused(const float* __restrict__ qp,
                const float* __restrict__ kp,
                const float* __restrict__ vp,
                const void*  __restrict__ mp,
                const float* __restrict__ bp,
                float* __restrict__ outp,
                float* __restrict__ attnp)
{
    __shared__ __align__(16) unsigned short Pbig[16 * 2048];      // 64 KB
    __shared__ __align__(16) unsigned short ArenaH[NW][16 * 64];  // 32 KB (f16 pivot/Lsum)

    const int tid  = threadIdx.x;
    const int w    = tid >> 6;          // wave id: owns k in [128w, 128w+128)
    const int lane = tid & 63;
    const int l15  = lane & 15;
    const int g    = lane >> 4;

    // mask layout probe — block-uniform exit BEFORE any barrier
    const unsigned int* mw = (const unsigned int*)mp;
    if ((__any((int)(mw[lane & 31] > 1u)) != 0) != ISBYTE) return;

    const int bid  = blockIdx.x;
    const int orig = (bid & 7) * 512 + (bid >> 3);   // bijective XCD swizzle (4096 blocks)
    const int h    = orig >> 8;                      // 2 heads per XCD
    const int rem  = orig & 255;
    const int qt   = rem >> 1;
    const int b    = rem & 1;                        // b-pair adjacent -> bias L2 share
    const int bh   = b * NH + h;
    const int qbase = qt * 16;
    const int kw   = w * KSPAN;

    const float* kbh = kp + (size_t)bh * SEQ * DH;
    const float* vbh = vp + (size_t)bh * SEQ * DH;
    char* pivot = (char*)&ArenaH[w][0];              // 16 rows x 128B (f16)
    char* pbig  = (char*)Pbig;

    // Q fragment (B-operand of swapped QK^T), prescaled by 1/8
    bf16x8 qf0, qf1;
    {
        const float* qb = qp + ((size_t)bh * SEQ + qbase + l15) * DH + g * 8;
        #pragma unroll
        for (int j = 0; j < 8; ++j) {
            qf0[j] = (short)f2bf(qb[j]      * 0.125f);
            qf1[j] = (short)f2bf(qb[32 + j] * 0.125f);
        }
    }

    struct KS { f32x4 k[2][4]; };
    auto load_k = [&](int tk, KS& R) {               // tk = subtile idx 0..3 in wave span
        const int kb = kw + tk * SUBT;
        #pragma unroll
        for (int mb = 0; mb < 2; ++mb) {
            const float* arow = kbh + (size_t)(kb + 16 * mb + l15) * DH + g * 8;
            R.k[mb][0] = *(const f32x4*)(arow);
            R.k[mb][1] = *(const f32x4*)(arow + 4);
            R.k[mb][2] = *(const f32x4*)(arow + 32);
            R.k[mb][3] = *(const f32x4*)(arow + 36);
        }
    };

    auto produce = [&](const KS& R, int s2) {        // s2 = subtile within chunk (0/1)
        #pragma unroll
        for (int mb = 0; mb < 2; ++mb) {
            union { bf16x8 v; unsigned int u[4]; } A0, A1;
            A0.u[0] = pkt(R.k[mb][0][0], R.k[mb][0][1]);
            A0.u[1] = pkt(R.k[mb][0][2], R.k[mb][0][3]);
            A0.u[2] = pkt(R.k[mb][1][0], R.k[mb][1][1]);
            A0.u[3] = pkt(R.k[mb][1][2], R.k[mb][1][3]);
            A1.u[0] = pkt(R.k[mb][2][0], R.k[mb][2][1]);
            A1.u[1] = pkt(R.k[mb][2][2], R.k[mb][2][3]);
            A1.u[2] = pkt(R.k[mb][3][0], R.k[mb][3][1]);
            A1.u[3] = pkt(R.k[mb][3][2], R.k[mb][3][3]);
            f32x4 c = (f32x4){0.f, 0.f, 0.f, 0.f};
            __builtin_amdgcn_s_setprio(1);
            c = __builtin_amdgcn_mfma_f32_16x16x32_bf16(A0.v, qf0, c, 0, 0, 0);
            c = __builtin_amdgcn_mfma_f32_16x16x32_bf16(A1.v, qf1, c, 0, 0, 0);
            __builtin_amdgcn_s_setprio(0);
            // raw scores (pre-bias, |s|<~6) -> f16 pivot (RNE), 8B per lane
            union { f16x4 h; u32x2 u; } hc;
            hc.h[0] = (_Float16)c[0];  hc.h[1] = (_Float16)c[1];
            hc.h[2] = (_Float16)c[2];  hc.h[3] = (_Float16)c[3];
            const int byo = (64 * s2 + 32 * mb + 8 * g) ^ ((l15 & 7) << 4);
            *(u32x2*)(pivot + l15 * 128 + byo) = hc.u;
        }
    };

    auto load_bias = [&](int c, f32x4* B) {          // contiguous: 4 rows x 256B per instr
        #pragma unroll
        for (int i = 0; i < 4; ++i)
            B[i] = *(const f32x4*)(bp + ((size_t)h * SEQ + qbase + 4 * i + g) * SEQ
                                   + kw + c * CHUNK + 4 * l15);
    };

    float rs[4] = {0.f, 0.f, 0.f, 0.f};              // row partials (row = 4i+g)

    auto consume = [&](int c, const f32x4* B) {
        #pragma unroll
        for (int i = 0; i < 4; ++i) {
            const int qr = 4 * i + g;                // local row 0..15
            int m4[4];
            if constexpr (ISBYTE) {
                unsigned int mk = *(const unsigned int*)((const unsigned char*)mp +
                    ((size_t)b * SEQ + qbase + qr) * SEQ + kw + c * CHUNK + 4 * l15);
                #pragma unroll
                for (int j = 0; j < 4; ++j) m4[j] = (int)((mk >> (8 * j)) & 0xFFu);
            } else {
                i32x4 mk = *(const i32x4*)((const int*)mp +
                    ((size_t)b * SEQ + qbase + qr) * SEQ + kw + c * CHUNK + 4 * l15);
                #pragma unroll
                for (int j = 0; j < 4; ++j) m4[j] = mk[j];
            }
            union { u32x2 u; f16x4 hh; } hv;
            hv.u = *(const u32x2*)(pivot + qr * 128 + ((8 * l15) ^ ((qr & 7) << 4)));
            f32x4 pa;
            #pragma unroll
            for (int j = 0; j < 4; ++j)
                pa[j] = m4[j] ? 0.0f : __expf((float)hv.hh[j] + B[i][j]);
            rs[i] += pa[0] + pa[1] + pa[2] + pa[3];
            u32x2 pw;
            pw[0] = pkt(pa[0], pa[1]);
            pw[1] = pkt(pa[2], pa[3]);
            const int byo = (2 * kw + 128 * c + 8 * l15) ^ ((qr & 7) << 4);
            *(u32x2*)(pbig + qr * 4096 + byo) = pw;
        }
    };

    f32x4 accO[4];   // accO[nb][rr] = O[q=qbase+4g+rr][d=16nb+l15] (this wave's k-span)
    #pragma unroll
    for (int i = 0; i < 4; ++i) accO[i] = (f32x4){0.f, 0.f, 0.f, 0.f};

    auto pv = [&](int c) {
        #pragma unroll
        for (int ks2 = 0; ks2 < 2; ++ks2) {
            const int colg = kw + (2 * c + ks2) * SUBT;
            const int byo = (2 * colg + 16 * g) ^ ((l15 & 7) << 4);
            bf16x8 pf = *(const bf16x8*)(pbig + l15 * 4096 + byo);
            const float* vb2 = vbh + (size_t)colg * DH + 512 * g + l15;
            union { bf16x8 v; unsigned int u[4]; } vf[4];
            #pragma unroll
            for (int nb = 0; nb < 4; ++nb)
                #pragma unroll
                for (int i2 = 0; i2 < 4; ++i2)
                    vf[nb].u[i2] = pkt(vb2[(2 * i2) * 64 + 16 * nb],
                                       vb2[(2 * i2 + 1) * 64 + 16 * nb]);
            __builtin_amdgcn_s_setprio(1);
            #pragma unroll
            for (int nb = 0; nb < 4; ++nb)
                accO[nb] = __builtin_amdgcn_mfma_f32_16x16x32_bf16(pf, vf[nb].v, accO[nb], 0, 0, 0);
            __builtin_amdgcn_s_setprio(0);
        }
    };

    // ========= phase 1: 2 chunks; bias D=1-ahead, K D=2 (guarded reissue) =========
    {
        KS RA, RB;
        f32x4 BA[4], BB[4];
        load_k(0, RA);
        load_k(1, RB);
        load_bias(0, BA);

        #pragma unroll
        for (int c = 0; c < NCHK; ++c) {
            f32x4* Bcur = (c & 1) ? BB : BA;
            f32x4* Bnxt = (c & 1) ? BA : BB;
            if (c < NCHK - 1) load_bias(c + 1, Bnxt);
            produce(RA, 0);  if (c < NCHK - 1) load_k(2 * c + 2, RA);
            produce(RB, 1);  if (c < NCHK - 1) load_k(2 * c + 3, RB);
            consume(c, Bcur);
            pv(c);
        }
    }

    // row-sum partials -> Lsum overlay on own (dead) pivot
    {
        float* lsw = (float*)&ArenaH[w][0];
        #pragma unroll
        for (int i = 0; i < 4; ++i) {
            float t = rs[i];
            t += __shfl_xor(t, 1, 64);
            t += __shfl_xor(t, 2, 64);
            t += __shfl_xor(t, 4, 64);
            t += __shfl_xor(t, 8, 64);
            if (l15 == 0) lsw[4 * i + g] = t;
        }
    }

    __syncthreads();                                 // barrier 1: Lsum ready

    // ========= phase 2: normalize own span, write attn ONCE =========
    float rv[4];
    #pragma unroll
    for (int i = 0; i < 4; ++i) {
        float s = 0.f;
        #pragma unroll
        for (int ww = 0; ww < NW; ++ww) s += ((const float*)&ArenaH[ww][0])[4 * i + g];
        rv[i] = 1.0f / s;
    }

    #pragma unroll
    for (int i = 0; i < 4; ++i) {
        const int qr = 4 * i + g;
        const int byo = (2 * kw + 16 * l15) ^ ((qr & 7) << 4);
        bf16x8 pb8 = *(const bf16x8*)(pbig + qr * 4096 + byo);
        f32x4 o0, o1;
        #pragma unroll
        for (int j = 0; j < 4; ++j) {
            o0[j] = bfu2f((unsigned short)pb8[j])     * rv[i];
            o1[j] = bfu2f((unsigned short)pb8[4 + j]) * rv[i];
        }
        float* ap = attnp + ((size_t)bh * SEQ + qbase + qr) * SEQ + kw + 8 * l15;
        *(f32x4*)ap       = o0;
        *(f32x4*)(ap + 4) = o1;
    }

    __syncthreads();                                 // barrier 2: Pbig fully dead

    // accO deposit into Pbig (4 KB per wave = 64 KB exactly), then wave 0 combines
    {
        float* dep = (float*)pbig + w * 1024;
        #pragma unroll
        for (int rr = 0; rr < 4; ++rr)
            #pragma unroll
            for (int nb = 0; nb < 4; ++nb)
                dep[(4 * g + rr) * 64 + 16 * nb + l15] = accO[nb][rr];
    }

    __syncthreads();                                 // barrier 3: deposits visible

    if (w == 0) {
        const int d = lane;
        #pragma unroll
        for (int r = 0; r < 16; ++r) {
            float s = 0.f, o = 0.f;
            #pragma unroll
            for (int ww = 0; ww < NW; ++ww) {
                s += ((const float*)&ArenaH[ww][0])[r];
                o += ((const float*)pbig)[ww * 1024 + r * 64 + d];
            }
            outp[((size_t)bh * SEQ + qbase + r) * DH + d] = o / s;
        }
    }
}

extern "C" void kernel_launch(void* const* d_in, const int* in_sizes, int n_in,
                              void* d_out, int out_size, void* d_ws, size_t ws_size,
                              hipStream_t stream) {
    const float* qp = (const float*)d_in[0];
    const float* kp = (const float*)d_in[1];
    const float* vp = (const float*)d_in[2];
    const void*  mp = d_in[3];
    const float* bp = (const float*)d_in[4];

    float* outp  = (float*)d_out;
    float* attnp = outp + (size_t)BATCH * NH * SEQ * DH;   // out first, then attn (f32)

    dim3 grid(BATCH * NH * (SEQ / 16)), block(1024);       // 4096 blocks x 16 waves
    // mask layout resolved on-device; mismatched instantiation exits immediately
    sdpa_fused<true ><<<grid, block, 0, stream>>>(qp, kp, vp, mp, bp, outp, attnp);
    sdpa_fused<false><<<grid, block, 0, stream>>>(qp, kp, vp, mp, bp, outp, attnp);
}

// Round 23
// 889.822 us; speedup vs baseline: 1.3266x; 1.3266x over previous
//
#include <hip/hip_runtime.h>

#define BATCH 2
#define NH    16
#define SEQ   2048
#define DH    64
#define NW    8             // waves per block
#define KSPAN 256           // k-cols per wave
#define CHUNK 64            // k-cols per chunk
#define NCHK  (KSPAN/CHUNK) // 4 chunks per wave
#define SUBT  32            // MFMA subtile cols

typedef __attribute__((ext_vector_type(8))) short          bf16x8;
typedef __attribute__((ext_vector_type(4))) float          f32x4;
typedef __attribute__((ext_vector_type(2))) unsigned int   u32x2;
typedef __attribute__((ext_vector_type(4))) int            i32x4;

__device__ __forceinline__ unsigned short f2bf(float f) {   // RNE (Q only)
    union { float f; unsigned int i; } c;
    c.f = f;
    unsigned int x = c.i;
    x += 0x7fffu + ((x >> 16) & 1u);
    return (unsigned short)(x >> 16);
}
__device__ __forceinline__ unsigned int pkt(float lo, float hi) {   // trunc bf16 pair
    union { float f; unsigned int u; } a, b;
    a.f = lo; b.f = hi;
    return (b.u & 0xFFFF0000u) | (a.u >> 16);
}
__device__ __forceinline__ float bfu2f(unsigned short u) {
    union { unsigned int i; float f; } c;
    c.i = ((unsigned int)u) << 16;
    return c.f;
}

// Single-pass SDPA (r17 structure, 551us best) + mask & V prefetch:
// every long-latency input (K, bias, mask, V) now issued >= 1 chunk before use.
template<bool ISBYTE>
__global__ __launch_bounds__(512, 2)
void sdpa_fused(const float* __restrict__ qp,
                const float* __restrict__ kp,
                const float* __restrict__ vp,
                const void*  __restrict__ mp,
                const float* __restrict__ bp,
                float* __restrict__ outp,
                float* __restrict__ attnp)
{
    __shared__ __align__(16) unsigned short Pbig[16 * 2048];          // 64 KB
    __shared__ __align__(16) float Arena[NW][16 * CHUNK];             // 32 KB (pivot / accO)
    __shared__ float Lsum[NW][16];                                    // row-sum partials

    const int tid  = threadIdx.x;
    const int w    = tid >> 6;          // wave id: owns k in [256w, 256w+256)
    const int lane = tid & 63;
    const int l15  = lane & 15;
    const int g    = lane >> 4;

    // mask layout probe — block-uniform exit BEFORE any barrier
    const unsigned int* mw = (const unsigned int*)mp;
    if ((__any((int)(mw[lane & 31] > 1u)) != 0) != ISBYTE) return;

    const int bid  = blockIdx.x;
    const int orig = (bid & 7) * 512 + (bid >> 3);   // bijective XCD swizzle (4096 blocks)
    const int h    = orig >> 8;                      // 2 heads per XCD
    const int rem  = orig & 255;
    const int qt   = rem >> 1;
    const int b    = rem & 1;                        // b-pair adjacent -> bias L2 share
    const int bh   = b * NH + h;
    const int qbase = qt * 16;
    const int kw   = w * KSPAN;

    const float* kbh = kp + (size_t)bh * SEQ * DH;
    const float* vbh = vp + (size_t)bh * SEQ * DH;
    char* pivot = (char*)&Arena[w][0];               // 16 rows x 256B
    char* pbig  = (char*)Pbig;

    // Q fragment (B-operand of swapped QK^T), prescaled by 1/8
    bf16x8 qf0, qf1;
    {
        const float* qb = qp + ((size_t)bh * SEQ + qbase + l15) * DH + g * 8;
        #pragma unroll
        for (int j = 0; j < 8; ++j) {
            qf0[j] = (short)f2bf(qb[j]      * 0.125f);
            qf1[j] = (short)f2bf(qb[32 + j] * 0.125f);
        }
    }

    struct KS { f32x4 k[2][4]; };
    auto load_k = [&](int tk, KS& R) {               // tk = subtile idx 0..7 in wave span
        const int kb = kw + tk * SUBT;
        #pragma unroll
        for (int mb = 0; mb < 2; ++mb) {
            const float* arow = kbh + (size_t)(kb + 16 * mb + l15) * DH + g * 8;
            R.k[mb][0] = *(const f32x4*)(arow);
            R.k[mb][1] = *(const f32x4*)(arow + 4);
            R.k[mb][2] = *(const f32x4*)(arow + 32);
            R.k[mb][3] = *(const f32x4*)(arow + 36);
        }
    };

    auto produce = [&](const KS& R, int s2) {        // s2 = subtile within chunk (0/1)
        #pragma unroll
        for (int mb = 0; mb < 2; ++mb) {
            union { bf16x8 v; unsigned int u[4]; } A0, A1;
            A0.u[0] = pkt(R.k[mb][0][0], R.k[mb][0][1]);
            A0.u[1] = pkt(R.k[mb][0][2], R.k[mb][0][3]);
            A0.u[2] = pkt(R.k[mb][1][0], R.k[mb][1][1]);
            A0.u[3] = pkt(R.k[mb][1][2], R.k[mb][1][3]);
            A1.u[0] = pkt(R.k[mb][2][0], R.k[mb][2][1]);
            A1.u[1] = pkt(R.k[mb][2][2], R.k[mb][2][3]);
            A1.u[2] = pkt(R.k[mb][3][0], R.k[mb][3][1]);
            A1.u[3] = pkt(R.k[mb][3][2], R.k[mb][3][3]);
            f32x4 c = (f32x4){0.f, 0.f, 0.f, 0.f};
            __builtin_amdgcn_s_setprio(1);
            c = __builtin_amdgcn_mfma_f32_16x16x32_bf16(A0.v, qf0, c, 0, 0, 0);
            c = __builtin_amdgcn_mfma_f32_16x16x32_bf16(A1.v, qf1, c, 0, 0, 0);
            __builtin_amdgcn_s_setprio(0);
            const int byo = (128 * s2 + 64 * mb + 16 * g) ^ ((l15 & 7) << 4);
            *(f32x4*)(pivot + l15 * 256 + byo) = c;
        }
    };

    // bias + mask prefetch buffer (both streamed; the unused mask member is DCE'd)
    struct BM { f32x4 bias[4]; unsigned int m8[4]; i32x4 mi[4]; };
    auto load_bm = [&](int c, BM& B) {               // contiguous: 4 rows x 256B per instr
        #pragma unroll
        for (int i = 0; i < 4; ++i) {
            const int row = qbase + 4 * i + g;
            B.bias[i] = *(const f32x4*)(bp + ((size_t)h * SEQ + row) * SEQ
                                        + kw + c * CHUNK + 4 * l15);
            if constexpr (ISBYTE)
                B.m8[i] = *(const unsigned int*)((const unsigned char*)mp +
                           ((size_t)b * SEQ + row) * SEQ + kw + c * CHUNK + 4 * l15);
            else
                B.mi[i] = *(const i32x4*)((const int*)mp +
                           ((size_t)b * SEQ + row) * SEQ + kw + c * CHUNK + 4 * l15);
        }
    };

    float rs[4] = {0.f, 0.f, 0.f, 0.f};              // row partials (row = 4i+g)

    auto consume = [&](int c, const BM& B) {
        #pragma unroll
        for (int i = 0; i < 4; ++i) {
            const int qr = 4 * i + g;                // local row 0..15
            int m4[4];
            if constexpr (ISBYTE) {
                #pragma unroll
                for (int j = 0; j < 4; ++j) m4[j] = (int)((B.m8[i] >> (8 * j)) & 0xFFu);
            } else {
                #pragma unroll
                for (int j = 0; j < 4; ++j) m4[j] = B.mi[i][j];
            }
            f32x4 p = *(const f32x4*)(pivot + qr * 256 + ((16 * l15) ^ ((qr & 7) << 4)));
            f32x4 pa;
            #pragma unroll
            for (int j = 0; j < 4; ++j)
                pa[j] = m4[j] ? 0.0f : __expf(p[j] + B.bias[i][j]);
            rs[i] += pa[0] + pa[1] + pa[2] + pa[3];
            u32x2 pw;
            pw[0] = pkt(pa[0], pa[1]);
            pw[1] = pkt(pa[2], pa[3]);
            const int byo = (2 * kw + 128 * c + 8 * l15) ^ ((qr & 7) << 4);
            *(u32x2*)(pbig + qr * 4096 + byo) = pw;
        }
    };

    // V prefetch: one subtile (32 regs) per buffer, reloaded one chunk ahead
    struct VR { float v[4][8]; };
    auto load_v = [&](int colg, VR& V) {
        const float* vb2 = vbh + (size_t)colg * DH + 512 * g + l15;
        #pragma unroll
        for (int nb = 0; nb < 4; ++nb)
            #pragma unroll
            for (int j = 0; j < 8; ++j)
                V.v[nb][j] = vb2[j * 64 + 16 * nb];
    };

    f32x4 accO[4];   // accO[nb][rr] = O[q=qbase+4g+rr][d=16nb+l15] (this wave's k-span)
    #pragma unroll
    for (int i = 0; i < 4; ++i) accO[i] = (f32x4){0.f, 0.f, 0.f, 0.f};

    auto pv_sub = [&](int colg, const VR& V) {       // PV for one 32-k subtile, V resident
        const int byo = (2 * colg + 16 * g) ^ ((l15 & 7) << 4);
        bf16x8 pf = *(const bf16x8*)(pbig + l15 * 4096 + byo);
        union { bf16x8 v; unsigned int u[4]; } vf[4];
        #pragma unroll
        for (int nb = 0; nb < 4; ++nb)
            #pragma unroll
            for (int i2 = 0; i2 < 4; ++i2)
                vf[nb].u[i2] = pkt(V.v[nb][2 * i2], V.v[nb][2 * i2 + 1]);
        __builtin_amdgcn_s_setprio(1);
        #pragma unroll
        for (int nb = 0; nb < 4; ++nb)
            accO[nb] = __builtin_amdgcn_mfma_f32_16x16x32_bf16(pf, vf[nb].v, accO[nb], 0, 0, 0);
        __builtin_amdgcn_s_setprio(0);
    };

    // ========== phase 1: 4 chunks; K D=2, bias+mask D=1, V D=1 register pipelines =====
    {
        KS RA, RB;
        BM BA, BB;
        VR V0, V1;
        load_k(0, RA);
        load_k(1, RB);
        load_bm(0, BA);
        load_v(kw, V0);                              // chunk 0, subtile 0
        load_v(kw + SUBT, V1);                       // chunk 0, subtile 1

        #pragma unroll
        for (int c = 0; c < NCHK; ++c) {
            BM& Bcur = (c & 1) ? BB : BA;
            BM& Bnxt = (c & 1) ? BA : BB;
            if (c < NCHK - 1) load_bm(c + 1, Bnxt);
            produce(RA, 0);  load_k((2 * c + 2) & 7, RA);
            produce(RB, 1);  load_k((2 * c + 3) & 7, RB);
            consume(c, Bcur);
            pv_sub(kw + (2 * c) * SUBT, V0);
            load_v(kw + (((2 * c + 2) & 7) * SUBT), V0);   // next chunk sub0 (wrap: dead)
            pv_sub(kw + (2 * c + 1) * SUBT, V1);
            load_v(kw + (((2 * c + 3) & 7) * SUBT), V1);   // next chunk sub1
        }
    }

    // row-sum partials -> Lsum; accO -> Arena (unions the now-dead pivot)
    #pragma unroll
    for (int i = 0; i < 4; ++i) {
        float t = rs[i];
        t += __shfl_xor(t, 1, 64);
        t += __shfl_xor(t, 2, 64);
        t += __shfl_xor(t, 4, 64);
        t += __shfl_xor(t, 8, 64);
        if (l15 == 0) Lsum[w][4 * i + g] = t;
    }
    #pragma unroll
    for (int rr = 0; rr < 4; ++rr)
        #pragma unroll
        for (int nb = 0; nb < 4; ++nb)
            Arena[w][(4 * g + rr) * 64 + 16 * nb + l15] = accO[nb][rr];

    __syncthreads();

    // ========== phase 2: normalize own span, write attn ONCE ==========
    float rv[4];
    #pragma unroll
    for (int i = 0; i < 4; ++i) {
        float s = 0.f;
        #pragma unroll
        for (int ww = 0; ww < NW; ++ww) s += Lsum[ww][4 * i + g];
        rv[i] = 1.0f / s;
    }

    #pragma unroll
    for (int i = 0; i < 4; ++i) {
        const int qr = 4 * i + g;
        #pragma unroll
        for (int u = 0; u < 2; ++u) {
            const int byo = (2 * kw + 256 * u + 16 * l15) ^ ((qr & 7) << 4);
            bf16x8 pb8 = *(const bf16x8*)(pbig + qr * 4096 + byo);
            f32x4 o0, o1;
            #pragma unroll
            for (int j = 0; j < 4; ++j) {
                o0[j] = bfu2f((unsigned short)pb8[j])     * rv[i];
                o1[j] = bfu2f((unsigned short)pb8[4 + j]) * rv[i];
            }
            float* ap = attnp + ((size_t)bh * SEQ + qbase + qr) * SEQ
                        + kw + u * 128 + 8 * l15;
            *(f32x4*)ap       = o0;
            *(f32x4*)(ap + 4) = o1;
        }
    }

    // out: wave 0 combines the 8 deposits + normalizes (16 rows x 64 d)
    if (w == 0) {
        const int d = lane;
        #pragma unroll
        for (int r = 0; r < 16; ++r) {
            float s = 0.f, o = 0.f;
            #pragma unroll
            for (int ww = 0; ww < NW; ++ww) {
                s += Lsum[ww][r];
                o += Arena[ww][r * 64 + d];
            }
            outp[((size_t)bh * SEQ + qbase + r) * DH + d] = o / s;
        }
    }
}

extern "C" void kernel_launch(void* const* d_in, const int* in_sizes, int n_in,
                              void* d_out, int out_size, void* d_ws, size_t ws_size,
                              hipStream_t stream) {
    const float* qp = (const float*)d_in[0];
    const float* kp = (const float*)d_in[1];
    const float* vp = (const float*)d_in[2];
    const void*  mp = d_in[3];
    const float* bp = (const float*)d_in[4];

    float* outp  = (float*)d_out;
    float* attnp = outp + (size_t)BATCH * NH * SEQ * DH;   // out first, then attn (f32)

    dim3 grid(BATCH * NH * (SEQ / 16)), block(512);        // 4096 blocks x 8 waves
    // mask layout resolved on-device; mismatched instantiation exits immediately
    sdpa_fused<true ><<<grid, block, 0, stream>>>(qp, kp, vp, mp, bp, outp, attnp);
    sdpa_fused<false><<<grid, block, 0, stream>>>(qp, kp, vp, mp, bp, outp, attnp);
}

// Round 24
// 490.314 us; speedup vs baseline: 2.4075x; 1.8148x over previous
//
#include <hip/hip_runtime.h>

#define BATCH 2
#define NH    16
#define SEQ   2048
#define DH    64
#define NW    8             // waves per block
#define KSPAN 256           // k-cols per wave
#define CHUNK 64            // k-cols per chunk
#define NCHK  (KSPAN/CHUNK) // 4 chunks per wave
#define SUBT  32            // MFMA subtile cols
#define KVELEMS ((size_t)BATCH * NH * SEQ * DH)     // 4,194,304 elems per tensor

typedef __attribute__((ext_vector_type(8))) short          bf16x8;
typedef __attribute__((ext_vector_type(4))) float          f32x4;
typedef __attribute__((ext_vector_type(2))) unsigned int   u32x2;
typedef __attribute__((ext_vector_type(4))) unsigned short u16x4;
typedef __attribute__((ext_vector_type(4))) int            i32x4;

__device__ __forceinline__ unsigned short f2bf(float f) {   // RNE
    union { float f; unsigned int i; } c;
    c.f = f;
    unsigned int x = c.i;
    x += 0x7fffu + ((x >> 16) & 1u);
    return (unsigned short)(x >> 16);
}
__device__ __forceinline__ unsigned int pkt(float lo, float hi) {   // trunc bf16 pair
    union { float f; unsigned int u; } a, b;
    a.f = lo; b.f = hi;
    return (b.u & 0xFFFF0000u) | (a.u >> 16);
}
__device__ __forceinline__ float bfu2f(unsigned short u) {
    union { unsigned int i; float f; } c;
    c.i = ((unsigned int)u) << 16;
    return c.f;
}

// ============ pre-pass 1: K f32 -> bf16, same [bh][k][d] layout ============
__global__ __launch_bounds__(256)
void cvt_k(const float* __restrict__ src, unsigned short* __restrict__ dst)
{
    const size_t total = KVELEMS / 4;
    for (size_t i = (size_t)blockIdx.x * 256 + threadIdx.x; i < total;
         i += (size_t)gridDim.x * 256) {
        f32x4 v = ((const f32x4*)src)[i];
        u16x4 o;
        #pragma unroll
        for (int j = 0; j < 4; ++j) o[j] = f2bf(v[j]);
        ((u16x4*)dst)[i] = o;
    }
}

// ============ pre-pass 2: V f32 [bh][k][d] -> bf16 TRANSPOSED [bh][d][k] ============
__global__ __launch_bounds__(256)
void cvt_vt(const float* __restrict__ vp, unsigned short* __restrict__ vt)
{
    __shared__ unsigned short T[64][72];             // 64k x 64d tile, padded
    const int bh = blockIdx.x >> 5, kt = blockIdx.x & 31;
    const int t  = threadIdx.x;
    const int r  = t >> 2, c0 = (t & 3) * 16;        // stage: row r, 16 cols
    const float* src = vp + ((size_t)bh * SEQ + kt * 64 + r) * DH + c0;
    #pragma unroll
    for (int j = 0; j < 4; ++j) {
        f32x4 v = *(const f32x4*)(src + 4 * j);
        #pragma unroll
        for (int jj = 0; jj < 4; ++jj) T[r][c0 + 4 * j + jj] = f2bf(v[jj]);
    }
    __syncthreads();
    const int d = t >> 2, k0 = (t & 3) * 16;         // emit: d-row, 16 k-cols
    unsigned short* dst = vt + ((size_t)bh * DH + d) * SEQ + kt * 64 + k0;
    #pragma unroll
    for (int j = 0; j < 4; ++j) {
        u16x4 o;
        #pragma unroll
        for (int jj = 0; jj < 4; ++jj) o[jj] = T[k0 + 4 * j + jj][d];
        *(u16x4*)(dst + 4 * j) = o;
    }
}

// ============ fused single-pass SDPA (r17 structure; PRE: bf16 K + transposed V) ============
template<bool ISBYTE, bool PRE>
__global__ __launch_bounds__(512, 2)
void sdpa_fused(const float* __restrict__ qp,
                const float* __restrict__ kp,
                const float* __restrict__ vp,
                const void*  __restrict__ mp,
                const float* __restrict__ bp,
                const unsigned short* __restrict__ kb16,
                const unsigned short* __restrict__ vt16,
                float* __restrict__ outp,
                float* __restrict__ attnp)
{
    __shared__ __align__(16) unsigned short Pbig[16 * 2048];          // 64 KB
    __shared__ __align__(16) float Arena[NW][16 * CHUNK];             // 32 KB (pivot/accO)
    __shared__ float Lsum[NW][16];

    const int tid  = threadIdx.x;
    const int w    = tid >> 6;
    const int lane = tid & 63;
    const int l15  = lane & 15;
    const int g    = lane >> 4;

    const unsigned int* mw = (const unsigned int*)mp;
    if ((__any((int)(mw[lane & 31] > 1u)) != 0) != ISBYTE) return;

    const int bid  = blockIdx.x;
    const int orig = (bid & 7) * 512 + (bid >> 3);   // bijective XCD swizzle
    const int h    = orig >> 8;
    const int rem  = orig & 255;
    const int qt   = rem >> 1;
    const int b    = rem & 1;
    const int bh   = b * NH + h;
    const int qbase = qt * 16;
    const int kw   = w * KSPAN;

    const float* kbh = kp + (size_t)bh * SEQ * DH;
    const float* vbh = vp + (size_t)bh * SEQ * DH;
    const unsigned short* kbh16 = kb16 + (size_t)bh * SEQ * DH;
    const unsigned short* vth16 = vt16 + ((size_t)bh * DH + l15) * SEQ;   // +16nb*SEQ later
    char* pivot = (char*)&Arena[w][0];
    char* pbig  = (char*)Pbig;

    bf16x8 qf0, qf1;
    {
        const float* qb = qp + ((size_t)bh * SEQ + qbase + l15) * DH + g * 8;
        #pragma unroll
        for (int j = 0; j < 8; ++j) {
            qf0[j] = (short)f2bf(qb[j]      * 0.125f);
            qf1[j] = (short)f2bf(qb[32 + j] * 0.125f);
        }
    }

    struct KS { f32x4 kf[2][4]; bf16x8 kh[2][2]; };  // unused half is SROA-eliminated
    auto load_k = [&](int tk, KS& R) {
        const int kb = kw + tk * SUBT;
        #pragma unroll
        for (int mb = 0; mb < 2; ++mb) {
            if constexpr (PRE) {
                const unsigned short* arow = kbh16 + (size_t)(kb + 16 * mb + l15) * DH + g * 8;
                R.kh[mb][0] = *(const bf16x8*)(arow);
                R.kh[mb][1] = *(const bf16x8*)(arow + 32);
            } else {
                const float* arow = kbh + (size_t)(kb + 16 * mb + l15) * DH + g * 8;
                R.kf[mb][0] = *(const f32x4*)(arow);
                R.kf[mb][1] = *(const f32x4*)(arow + 4);
                R.kf[mb][2] = *(const f32x4*)(arow + 32);
                R.kf[mb][3] = *(const f32x4*)(arow + 36);
            }
        }
    };

    auto produce = [&](const KS& R, int s2) {
        #pragma unroll
        for (int mb = 0; mb < 2; ++mb) {
            bf16x8 A0, A1;
            if constexpr (PRE) {
                A0 = R.kh[mb][0];
                A1 = R.kh[mb][1];
            } else {
                union { bf16x8 v; unsigned int u[4]; } B0, B1;
                B0.u[0] = pkt(R.kf[mb][0][0], R.kf[mb][0][1]);
                B0.u[1] = pkt(R.kf[mb][0][2], R.kf[mb][0][3]);
                B0.u[2] = pkt(R.kf[mb][1][0], R.kf[mb][1][1]);
                B0.u[3] = pkt(R.kf[mb][1][2], R.kf[mb][1][3]);
                B1.u[0] = pkt(R.kf[mb][2][0], R.kf[mb][2][1]);
                B1.u[1] = pkt(R.kf[mb][2][2], R.kf[mb][2][3]);
                B1.u[2] = pkt(R.kf[mb][3][0], R.kf[mb][3][1]);
                B1.u[3] = pkt(R.kf[mb][3][2], R.kf[mb][3][3]);
                A0 = B0.v; A1 = B1.v;
            }
            f32x4 c = (f32x4){0.f, 0.f, 0.f, 0.f};
            __builtin_amdgcn_s_setprio(1);
            c = __builtin_amdgcn_mfma_f32_16x16x32_bf16(A0, qf0, c, 0, 0, 0);
            c = __builtin_amdgcn_mfma_f32_16x16x32_bf16(A1, qf1, c, 0, 0, 0);
            __builtin_amdgcn_s_setprio(0);
            const int byo = (128 * s2 + 64 * mb + 16 * g) ^ ((l15 & 7) << 4);
            *(f32x4*)(pivot + l15 * 256 + byo) = c;
        }
    };

    auto load_bias = [&](int c, f32x4* B) {
        #pragma unroll
        for (int i = 0; i < 4; ++i)
            B[i] = *(const f32x4*)(bp + ((size_t)h * SEQ + qbase + 4 * i + g) * SEQ
                                   + kw + c * CHUNK + 4 * l15);
    };

    float rs[4] = {0.f, 0.f, 0.f, 0.f};

    auto consume = [&](int c, const f32x4* B) {
        #pragma unroll
        for (int i = 0; i < 4; ++i) {
            const int qr = 4 * i + g;
            int m4[4];
            if constexpr (ISBYTE) {
                unsigned int mk = *(const unsigned int*)((const unsigned char*)mp +
                    ((size_t)b * SEQ + qbase + qr) * SEQ + kw + c * CHUNK + 4 * l15);
                #pragma unroll
                for (int j = 0; j < 4; ++j) m4[j] = (int)((mk >> (8 * j)) & 0xFFu);
            } else {
                i32x4 mk = *(const i32x4*)((const int*)mp +
                    ((size_t)b * SEQ + qbase + qr) * SEQ + kw + c * CHUNK + 4 * l15);
                #pragma unroll
                for (int j = 0; j < 4; ++j) m4[j] = mk[j];
            }
            f32x4 p = *(const f32x4*)(pivot + qr * 256 + ((16 * l15) ^ ((qr & 7) << 4)));
            f32x4 pa;
            #pragma unroll
            for (int j = 0; j < 4; ++j)
                pa[j] = m4[j] ? 0.0f : __expf(p[j] + B[i][j]);
            rs[i] += pa[0] + pa[1] + pa[2] + pa[3];
            u32x2 pw;
            pw[0] = pkt(pa[0], pa[1]);
            pw[1] = pkt(pa[2], pa[3]);
            const int byo = (2 * kw + 128 * c + 8 * l15) ^ ((qr & 7) << 4);
            *(u32x2*)(pbig + qr * 4096 + byo) = pw;
        }
    };

    f32x4 accO[4];
    #pragma unroll
    for (int i = 0; i < 4; ++i) accO[i] = (f32x4){0.f, 0.f, 0.f, 0.f};

    // PRE V: 4 contiguous bf16x8 loads per subtile from V^T
    auto load_vt = [&](int colg, bf16x8* F) {
        #pragma unroll
        for (int nb = 0; nb < 4; ++nb)
            F[nb] = *(const bf16x8*)(vth16 + (size_t)(16 * nb) * SEQ + colg + 8 * g);
    };
    auto pv_pre = [&](int colg, const bf16x8* F) {
        const int byo = (2 * colg + 16 * g) ^ ((l15 & 7) << 4);
        bf16x8 pf = *(const bf16x8*)(pbig + l15 * 4096 + byo);
        __builtin_amdgcn_s_setprio(1);
        #pragma unroll
        for (int nb = 0; nb < 4; ++nb)
            accO[nb] = __builtin_amdgcn_mfma_f32_16x16x32_bf16(pf, F[nb], accO[nb], 0, 0, 0);
        __builtin_amdgcn_s_setprio(0);
    };

    // fallback V path (r17 verbatim): scalar f32 + pkt at use
    auto pv_f32 = [&](int c) {
        #pragma unroll
        for (int ks2 = 0; ks2 < 2; ++ks2) {
            const int colg = kw + (2 * c + ks2) * SUBT;
            const int byo = (2 * colg + 16 * g) ^ ((l15 & 7) << 4);
            bf16x8 pf = *(const bf16x8*)(pbig + l15 * 4096 + byo);
            const float* vb2 = vbh + (size_t)colg * DH + 512 * g + l15;
            union { bf16x8 v; unsigned int u[4]; } vf[4];
            #pragma unroll
            for (int nb = 0; nb < 4; ++nb)
                #pragma unroll
                for (int i2 = 0; i2 < 4; ++i2)
                    vf[nb].u[i2] = pkt(vb2[(2 * i2) * 64 + 16 * nb],
                                       vb2[(2 * i2 + 1) * 64 + 16 * nb]);
            __builtin_amdgcn_s_setprio(1);
            #pragma unroll
            for (int nb = 0; nb < 4; ++nb)
                accO[nb] = __builtin_amdgcn_mfma_f32_16x16x32_bf16(pf, vf[nb].v, accO[nb], 0, 0, 0);
            __builtin_amdgcn_s_setprio(0);
        }
    };

    // ========== phase 1: 4 chunks; K D=2 ring, bias D=1, V chunk-batched (PRE) ==========
    {
        KS RA, RB;
        f32x4 BA[4], BB[4];
        bf16x8 V0[4], V1[4];
        load_k(0, RA);
        load_k(1, RB);
        load_bias(0, BA);

        #pragma unroll
        for (int c = 0; c < NCHK; ++c) {
            f32x4* Bcur = (c & 1) ? BB : BA;
            f32x4* Bnxt = (c & 1) ? BA : BB;
            if constexpr (PRE) load_vt(kw + (2 * c) * SUBT, V0);       // cover: produce+consume
            if (c < NCHK - 1) load_bias(c + 1, Bnxt);
            produce(RA, 0);  load_k((2 * c + 2) & 7, RA);
            produce(RB, 1);  load_k((2 * c + 3) & 7, RB);
            if constexpr (PRE) load_vt(kw + (2 * c + 1) * SUBT, V1);
            consume(c, Bcur);
            if constexpr (PRE) {
                pv_pre(kw + (2 * c) * SUBT, V0);
                pv_pre(kw + (2 * c + 1) * SUBT, V1);
            } else {
                pv_f32(c);
            }
        }
    }

    #pragma unroll
    for (int i = 0; i < 4; ++i) {
        float t = rs[i];
        t += __shfl_xor(t, 1, 64);
        t += __shfl_xor(t, 2, 64);
        t += __shfl_xor(t, 4, 64);
        t += __shfl_xor(t, 8, 64);
        if (l15 == 0) Lsum[w][4 * i + g] = t;
    }
    #pragma unroll
    for (int rr = 0; rr < 4; ++rr)
        #pragma unroll
        for (int nb = 0; nb < 4; ++nb)
            Arena[w][(4 * g + rr) * 64 + 16 * nb + l15] = accO[nb][rr];

    __syncthreads();

    float rv[4];
    #pragma unroll
    for (int i = 0; i < 4; ++i) {
        float s = 0.f;
        #pragma unroll
        for (int ww = 0; ww < NW; ++ww) s += Lsum[ww][4 * i + g];
        rv[i] = 1.0f / s;
    }

    #pragma unroll
    for (int i = 0; i < 4; ++i) {
        const int qr = 4 * i + g;
        #pragma unroll
        for (int u = 0; u < 2; ++u) {
            const int byo = (2 * kw + 256 * u + 16 * l15) ^ ((qr & 7) << 4);
            bf16x8 pb8 = *(const bf16x8*)(pbig + qr * 4096 + byo);
            f32x4 o0, o1;
            #pragma unroll
            for (int j = 0; j < 4; ++j) {
                o0[j] = bfu2f((unsigned short)pb8[j])     * rv[i];
                o1[j] = bfu2f((unsigned short)pb8[4 + j]) * rv[i];
            }
            float* ap = attnp + ((size_t)bh * SEQ + qbase + qr) * SEQ
                        + kw + u * 128 + 8 * l15;
            *(f32x4*)ap       = o0;
            *(f32x4*)(ap + 4) = o1;
        }
    }

    if (w == 0) {
        const int d = lane;
        #pragma unroll
        for (int r = 0; r < 16; ++r) {
            float s = 0.f, o = 0.f;
            #pragma unroll
            for (int ww = 0; ww < NW; ++ww) {
                s += Lsum[ww][r];
                o += Arena[ww][r * 64 + d];
            }
            outp[((size_t)bh * SEQ + qbase + r) * DH + d] = o / s;
        }
    }
}

extern "C" void kernel_launch(void* const* d_in, const int* in_sizes, int n_in,
                              void* d_out, int out_size, void* d_ws, size_t ws_size,
                              hipStream_t stream) {
    const float* qp = (const float*)d_in[0];
    const float* kp = (const float*)d_in[1];
    const float* vp = (const float*)d_in[2];
    const void*  mp = d_in[3];
    const float* bp = (const float*)d_in[4];

    float* outp  = (float*)d_out;
    float* attnp = outp + (size_t)BATCH * NH * SEQ * DH;   // out first, then attn (f32)

    unsigned short* kb16 = (unsigned short*)d_ws;
    unsigned short* vt16 = kb16 + KVELEMS;
    const bool usePre = ws_size >= 2 * KVELEMS * sizeof(unsigned short);   // 16.8 MB

    dim3 grid(BATCH * NH * (SEQ / 16)), block(512);

    if (usePre) {
        cvt_k <<<dim3(1024), dim3(256), 0, stream>>>(kp, kb16);
        cvt_vt<<<dim3(BATCH * NH * 32), dim3(256), 0, stream>>>(vp, vt16);
        sdpa_fused<true , true ><<<grid, block, 0, stream>>>(qp, kp, vp, mp, bp, kb16, vt16, outp, attnp);
        sdpa_fused<false, true ><<<grid, block, 0, stream>>>(qp, kp, vp, mp, bp, kb16, vt16, outp, attnp);
    } else {
        sdpa_fused<true , false><<<grid, block, 0, stream>>>(qp, kp, vp, mp, bp, kb16, vt16, outp, attnp);
        sdpa_fused<false, false><<<grid, block, 0, stream>>>(qp, kp, vp, mp, bp, kb16, vt16, outp, attnp);
    }
}